// Round 1
// baseline (6187.958 us; speedup 1.0000x reference)
//
#include <hip/hip_runtime.h>
#include <math.h>

// Problem constants (from reference): B=16, XL=2048, YL=2048, D=1024
// Pipeline per batch b:
//   xp = relu(x_b @ W^T + bias)          [2048x1024, K=1024]
//   yp = relu(y_b @ W^T + bias)          [2048x1024, K=1024]
//   sc = xp @ yp^T, masked cols -> -inf  [2048x2048, K=1024]
//   softmax rows of sc
//   out_b = sc @ y_b                     [2048x1024, K=2048]

#define TILE_BM 64
#define TILE_BN 64
#define TILE_BK 16
#define LDS_PAD 68   // row stride (floats) for [BK][..] tiles; keeps 16B align, 2-way max conflict

// C = op(A @ B') where:
//   BT=true:  B is (N,K) row-major (k-contiguous)  -> C[m,n] = sum_k A[m,k]*B[n,k]
//   BT=false: B is (K,N) row-major                 -> C[m,n] = sum_k A[m,k]*B[k,n]
// RELU: C = relu(C + bias[n]); MASK: mask[n]!=0 -> C[m,n] = -inf
template<bool BT, bool RELU, bool MASK>
__global__ __launch_bounds__(256)
void gemm_f32(const float* __restrict__ A, const float* __restrict__ Bm,
              const float* __restrict__ bias, const int* __restrict__ mask,
              float* __restrict__ C, int M, int N, int K)
{
    __shared__ float As[TILE_BK][LDS_PAD];
    __shared__ float Bs[TILE_BK][LDS_PAD];

    const int tid = threadIdx.x;
    const int tx = tid & 15;   // column group 0..15
    const int ty = tid >> 4;   // row group 0..15
    const int m0 = blockIdx.y * TILE_BM;
    const int n0 = blockIdx.x * TILE_BN;

    // loader indices: A tile is BM x BK (64x16): each thread loads one float4
    const int lr = tid >> 2;          // 0..63 (row in tile)
    const int lc = (tid & 3) << 2;    // 0,4,8,12 (k in tile)
    // for BT=false, B tile is BK x BN (16x64)
    const int br = tid >> 4;          // 0..15 (k row)
    const int bc = (tid & 15) << 2;   // 0..60 (n col)

    float acc[4][4] = {};

    for (int k0 = 0; k0 < K; k0 += TILE_BK) {
        // A tile: load BMxBK, store transposed As[k][m]
        {
            const float4 v = *reinterpret_cast<const float4*>(&A[(size_t)(m0 + lr) * K + k0 + lc]);
            As[lc + 0][lr] = v.x; As[lc + 1][lr] = v.y; As[lc + 2][lr] = v.z; As[lc + 3][lr] = v.w;
        }
        if (BT) {
            const float4 v = *reinterpret_cast<const float4*>(&Bm[(size_t)(n0 + lr) * K + k0 + lc]);
            Bs[lc + 0][lr] = v.x; Bs[lc + 1][lr] = v.y; Bs[lc + 2][lr] = v.z; Bs[lc + 3][lr] = v.w;
        } else {
            const float4 v = *reinterpret_cast<const float4*>(&Bm[(size_t)(k0 + br) * N + n0 + bc]);
            *reinterpret_cast<float4*>(&Bs[br][bc]) = v;
        }
        __syncthreads();

        #pragma unroll
        for (int kk = 0; kk < TILE_BK; ++kk) {
            const float4 av = *reinterpret_cast<const float4*>(&As[kk][ty << 2]);
            const float4 bv = *reinterpret_cast<const float4*>(&Bs[kk][tx << 2]);
            const float a_[4] = {av.x, av.y, av.z, av.w};
            const float b_[4] = {bv.x, bv.y, bv.z, bv.w};
            #pragma unroll
            for (int i = 0; i < 4; ++i)
                #pragma unroll
                for (int j = 0; j < 4; ++j)
                    acc[i][j] = fmaf(a_[i], b_[j], acc[i][j]);
        }
        __syncthreads();
    }

    // epilogue
    const int col = n0 + (tx << 2);
    float4 bv = {0.f, 0.f, 0.f, 0.f};
    if (RELU) bv = *reinterpret_cast<const float4*>(&bias[col]);
    int mk[4] = {0, 0, 0, 0};
    if (MASK) {
        mk[0] = mask[col + 0]; mk[1] = mask[col + 1];
        mk[2] = mask[col + 2]; mk[3] = mask[col + 3];
    }
    #pragma unroll
    for (int i = 0; i < 4; ++i) {
        float o[4];
        #pragma unroll
        for (int j = 0; j < 4; ++j) {
            float v = acc[i][j];
            if (RELU) {
                v += (&bv.x)[j];
                v = fmaxf(v, 0.f);
            }
            if (MASK) {
                if (mk[j]) v = -INFINITY;
            }
            o[j] = v;
        }
        float4 ov = {o[0], o[1], o[2], o[3]};
        *reinterpret_cast<float4*>(&C[(size_t)(m0 + (ty << 2) + i) * N + col]) = ov;
    }
}

// Row softmax over N=2048 (one block of 256 threads per row). -inf entries -> 0.
__global__ __launch_bounds__(256)
void softmax_rows(float* __restrict__ S, int N)
{
    const size_t row = blockIdx.x;
    float* p = S + row * (size_t)N;
    const int tid = threadIdx.x;

    float vals[8];
    float m = -INFINITY;
    #pragma unroll
    for (int u = 0; u < 8; ++u) {
        vals[u] = p[tid + u * 256];
        m = fmaxf(m, vals[u]);
    }
    #pragma unroll
    for (int off = 32; off >= 1; off >>= 1)
        m = fmaxf(m, __shfl_xor(m, off));

    __shared__ float redm[4];
    __shared__ float reds[4];
    if ((tid & 63) == 0) redm[tid >> 6] = m;
    __syncthreads();
    m = fmaxf(fmaxf(redm[0], redm[1]), fmaxf(redm[2], redm[3]));

    float s = 0.f;
    #pragma unroll
    for (int u = 0; u < 8; ++u) {
        vals[u] = __expf(vals[u] - m);
        s += vals[u];
    }
    #pragma unroll
    for (int off = 32; off >= 1; off >>= 1)
        s += __shfl_xor(s, off);
    if ((tid & 63) == 0) reds[tid >> 6] = s;
    __syncthreads();
    s = reds[0] + reds[1] + reds[2] + reds[3];

    const float inv = 1.f / s;
    #pragma unroll
    for (int u = 0; u < 8; ++u)
        p[tid + u * 256] = vals[u] * inv;
}

extern "C" void kernel_launch(void* const* d_in, const int* in_sizes, int n_in,
                              void* d_out, int out_size, void* d_ws, size_t ws_size,
                              hipStream_t stream)
{
    const float* x     = (const float*)d_in[0];  // (B, XL, D)
    const float* y     = (const float*)d_in[1];  // (B, YL, D)
    const int*   ymask = (const int*)d_in[2];    // (B, YL) bool->int32
    const float* W     = (const float*)d_in[3];  // (D, D)
    const float* bvec  = (const float*)d_in[4];  // (D,)
    float* out = (float*)d_out;

    const int B = 16, XL = 2048, YL = 2048, D = 1024;

    // per-batch workspace: xp (XL*D) + yp (YL*D) + sc (XL*YL) floats = 33.6 MB
    float* xp = (float*)d_ws;
    float* yp = xp + (size_t)XL * D;
    float* sc = yp + (size_t)YL * D;

    const dim3 thr(256);
    for (int b = 0; b < B; ++b) {
        const float* xb = x + (size_t)b * XL * D;
        const float* yb = y + (size_t)b * YL * D;
        const int*   mb = ymask + (size_t)b * YL;
        float* ob = out + (size_t)b * XL * D;

        // xp = relu(x_b @ W^T + bias)
        gemm_f32<true, true, false><<<dim3(D / TILE_BN, XL / TILE_BM), thr, 0, stream>>>(
            xb, W, bvec, nullptr, xp, XL, D, D);
        // yp = relu(y_b @ W^T + bias)
        gemm_f32<true, true, false><<<dim3(D / TILE_BN, YL / TILE_BM), thr, 0, stream>>>(
            yb, W, bvec, nullptr, yp, YL, D, D);
        // sc = xp @ yp^T (masked)
        gemm_f32<true, false, true><<<dim3(YL / TILE_BN, XL / TILE_BM), thr, 0, stream>>>(
            xp, yp, nullptr, mb, sc, XL, YL, D);
        // softmax rows
        softmax_rows<<<dim3(XL), thr, 0, stream>>>(sc, YL);
        // out_b = sc @ y_b
        gemm_f32<false, false, false><<<dim3(D / TILE_BN, XL / TILE_BM), thr, 0, stream>>>(
            sc, yb, nullptr, nullptr, ob, XL, D, YL);
    }
}

// Round 2
// 3354.228 us; speedup vs baseline: 1.8448x; 1.8448x over previous
//
#include <hip/hip_runtime.h>
#include <math.h>
#include <stdint.h>

// B=16, XL=YL=2048, D=1024.
// Pipeline per batch (all GEMMs: split-bf16 hi/lo, 3-pass MFMA 16x16x32):
//   p = relu([x_b; y_b] @ W^T + bias)      (4096x1024, K=1024) -> split bf16
//   sc = xp @ yp^T  (+mask -> -inf)        (2048x2048, K=1024) -> fp32
//   w  = softmax rows(sc)                  -> split bf16
//   out_b = w @ yT^T                       (2048x1024, K=2048) -> fp32
//
// Workspace layout (44 MB total):
//   Whi,Wlo: 2+2 MB | aHi,aLo ([x;y] row splits): 8+8 MB (sc fp32 16MB aliases)
//   yThi,yTlo: 4+4 MB | pHi,pLo: 8+8 MB (wHi,wLo alias after scores)

typedef __attribute__((ext_vector_type(8))) short bf16x8;
typedef __attribute__((ext_vector_type(4))) float f32x4;

__device__ __forceinline__ ushort f32_bf16_rne(float f) {
    uint32_t u = __float_as_uint(f);
    u += 0x7fffu + ((u >> 16) & 1u);
    return (ushort)(u >> 16);
}
__device__ __forceinline__ float bf16_f32(ushort h) {
    return __uint_as_float((uint32_t)h << 16);
}
__device__ __forceinline__ void split2(float f, ushort& h, ushort& l) {
    h = f32_bf16_rne(f);
    l = f32_bf16_rne(f - bf16_f32(h));
}

__device__ __forceinline__ void ld16(ushort* lds, const ushort* g) {
    __builtin_amdgcn_global_load_lds(
        (__attribute__((address_space(1))) void*)(g),
        (__attribute__((address_space(3))) void*)(lds), 16, 0, 0);
}

// C = A @ B^T with A,B given as bf16 hi/lo splits (A: MxK, B: NxK, k-contiguous).
// 3-pass: Ahi*Bhi + Ahi*Blo + Alo*Bhi.
// EPI 0: write fp32 C. EPI 1: relu(C+bias[n]) -> split bf16 (Chi,Clo).
// EPI 2: mask[n] ? -inf : C -> fp32.
template<int EPI>
__global__ __launch_bounds__(256) void gemm_split(
    const ushort* __restrict__ Ahi, const ushort* __restrict__ Alo,
    const ushort* __restrict__ Bhi, const ushort* __restrict__ Blo,
    const float* __restrict__ bias, const int* __restrict__ mask,
    float* __restrict__ Cf, ushort* __restrict__ Chi, ushort* __restrict__ Clo,
    int M, int N, int K)
{
    __shared__ ushort AsH[4096], AsL[4096], BsH[4096], BsL[4096]; // 128x32 each, 32 KB

    const int tid  = threadIdx.x;
    const int lane = tid & 63;
    const int wv   = tid >> 6;
    const int m0 = blockIdx.y * 128;
    const int n0 = blockIdx.x * 128;

    // staging: tile is 128 rows x 32 k (64 B/row). chunk0 = rows 0..63, chunk1 = 64..127.
    const int b0 = wv * 1024 + lane * 16;   // byte offset within chunk
    const int r0 = b0 >> 6;                 // 0..63
    const int c0 = (b0 & 63) >> 1;          // k element offset (0,8,16,24)
    const int r1 = r0 + 64;

    const ushort* gAh = Ahi + (size_t)m0 * K;
    const ushort* gAl = Alo + (size_t)m0 * K;
    const ushort* gBh = Bhi + (size_t)n0 * K;
    const ushort* gBl = Blo + (size_t)n0 * K;
    const size_t oA0 = (size_t)r0 * K + c0;
    const size_t oA1 = (size_t)r1 * K + c0;

    ushort* dAh0 = &AsH[wv * 512];        ushort* dAh1 = &AsH[2048 + wv * 512];
    ushort* dAl0 = &AsL[wv * 512];        ushort* dAl1 = &AsL[2048 + wv * 512];
    ushort* dBh0 = &BsH[wv * 512];        ushort* dBh1 = &BsH[2048 + wv * 512];
    ushort* dBl0 = &BsL[wv * 512];        ushort* dBl1 = &BsL[2048 + wv * 512];

    // compute mapping: wave grid 2x2, each wave 64x64; 4x4 fragments of 16x16
    const int fr = lane & 15;
    const int fq = lane >> 4;
    const int koff = fq * 8;
    const int wm = (wv >> 1) * 64;
    const int wn = (wv & 1) * 64;

    f32x4 acc[4][4];
    #pragma unroll
    for (int i = 0; i < 4; ++i)
        #pragma unroll
        for (int j = 0; j < 4; ++j)
            acc[i][j] = (f32x4){0.f, 0.f, 0.f, 0.f};

    for (int k0 = 0; k0 < K; k0 += 32) {
        ld16(dAh0, gAh + oA0 + k0);  ld16(dAh1, gAh + oA1 + k0);
        ld16(dAl0, gAl + oA0 + k0);  ld16(dAl1, gAl + oA1 + k0);
        ld16(dBh0, gBh + oA0 + k0);  ld16(dBh1, gBh + oA1 + k0);
        ld16(dBl0, gBl + oA0 + k0);  ld16(dBl1, gBl + oA1 + k0);
        __syncthreads();

        bf16x8 a[4], b[4], t[4];
        #pragma unroll
        for (int i = 0; i < 4; ++i)
            a[i] = *(const bf16x8*)&AsH[(wm + i * 16 + fr) * 32 + koff];
        #pragma unroll
        for (int j = 0; j < 4; ++j)
            b[j] = *(const bf16x8*)&BsH[(wn + j * 16 + fr) * 32 + koff];
        #pragma unroll
        for (int i = 0; i < 4; ++i)
            #pragma unroll
            for (int j = 0; j < 4; ++j)
                acc[i][j] = __builtin_amdgcn_mfma_f32_16x16x32_bf16(a[i], b[j], acc[i][j], 0, 0, 0);
        #pragma unroll
        for (int j = 0; j < 4; ++j)
            t[j] = *(const bf16x8*)&BsL[(wn + j * 16 + fr) * 32 + koff];
        #pragma unroll
        for (int i = 0; i < 4; ++i)
            #pragma unroll
            for (int j = 0; j < 4; ++j)
                acc[i][j] = __builtin_amdgcn_mfma_f32_16x16x32_bf16(a[i], t[j], acc[i][j], 0, 0, 0);
        #pragma unroll
        for (int i = 0; i < 4; ++i)
            a[i] = *(const bf16x8*)&AsL[(wm + i * 16 + fr) * 32 + koff];
        #pragma unroll
        for (int i = 0; i < 4; ++i)
            #pragma unroll
            for (int j = 0; j < 4; ++j)
                acc[i][j] = __builtin_amdgcn_mfma_f32_16x16x32_bf16(a[i], b[j], acc[i][j], 0, 0, 0);
        __syncthreads();
    }

    // epilogue: C[row][col], col = fr, row = fq*4 + r within each 16x16 fragment
    #pragma unroll
    for (int j = 0; j < 4; ++j) {
        const int col = n0 + wn + j * 16 + fr;
        float bb = 0.f;
        int mk = 0;
        if constexpr (EPI == 1) bb = bias[col];
        if constexpr (EPI == 2) mk = mask[col];
        #pragma unroll
        for (int i = 0; i < 4; ++i) {
            const int row = m0 + wm + i * 16 + fq * 4;
            #pragma unroll
            for (int r = 0; r < 4; ++r) {
                const float v = acc[i][j][r];
                const size_t idx = (size_t)(row + r) * N + col;
                if constexpr (EPI == 0) {
                    Cf[idx] = v;
                } else if constexpr (EPI == 1) {
                    float u = fmaxf(v + bb, 0.f);
                    ushort h, l; split2(u, h, l);
                    Chi[idx] = h; Clo[idx] = l;
                } else {
                    Cf[idx] = mk ? -INFINITY : v;
                }
            }
        }
    }
}

// elementwise fp32 -> bf16 hi/lo split, 4 elems/thread
__global__ __launch_bounds__(256) void split_arr(const float* __restrict__ in,
    ushort* __restrict__ hi, ushort* __restrict__ lo, int n4)
{
    const int i = blockIdx.x * 256 + threadIdx.x;
    if (i >= n4) return;
    const float4 v = reinterpret_cast<const float4*>(in)[i];
    ushort4 h, l;
    split2(v.x, h.x, l.x);
    split2(v.y, h.y, l.y);
    split2(v.z, h.z, l.z);
    split2(v.w, h.w, l.w);
    reinterpret_cast<ushort4*>(hi)[i] = h;
    reinterpret_cast<ushort4*>(lo)[i] = l;
}

// y (RxC fp32) -> row-major splits (rhi,rlo: RxC) and transposed splits (thi,tlo: CxR)
__global__ __launch_bounds__(256) void split_transpose(const float* __restrict__ y,
    ushort* __restrict__ rhi, ushort* __restrict__ rlo,
    ushort* __restrict__ thi, ushort* __restrict__ tlo, int R, int C)
{
    __shared__ float tile[32][33];
    const int tx = threadIdx.x, ty = threadIdx.y;
    const int c0 = blockIdx.x * 32, r0 = blockIdx.y * 32;
    #pragma unroll
    for (int k = 0; k < 4; ++k) {
        const int r = r0 + ty + k * 8;
        const float v = y[(size_t)r * C + c0 + tx];
        tile[ty + k * 8][tx] = v;
        ushort h, l; split2(v, h, l);
        rhi[(size_t)r * C + c0 + tx] = h;
        rlo[(size_t)r * C + c0 + tx] = l;
    }
    __syncthreads();
    #pragma unroll
    for (int k = 0; k < 4; ++k) {
        const int c = c0 + ty + k * 8;
        const float v = tile[tx][ty + k * 8];
        ushort h, l; split2(v, h, l);
        thi[(size_t)c * R + r0 + tx] = h;
        tlo[(size_t)c * R + r0 + tx] = l;
    }
}

// row softmax over N=2048, write split bf16 weights
__global__ __launch_bounds__(256) void softmax_split(const float* __restrict__ S,
    ushort* __restrict__ whi, ushort* __restrict__ wlo, int N)
{
    const size_t row = blockIdx.x;
    const float* p = S + row * (size_t)N;
    const int tid = threadIdx.x;

    float vals[8];
    float m = -INFINITY;
    #pragma unroll
    for (int u = 0; u < 8; ++u) {
        vals[u] = p[tid + u * 256];
        m = fmaxf(m, vals[u]);
    }
    #pragma unroll
    for (int off = 32; off >= 1; off >>= 1)
        m = fmaxf(m, __shfl_xor(m, off));

    __shared__ float redm[4], reds[4];
    if ((tid & 63) == 0) redm[tid >> 6] = m;
    __syncthreads();
    m = fmaxf(fmaxf(redm[0], redm[1]), fmaxf(redm[2], redm[3]));

    float s = 0.f;
    #pragma unroll
    for (int u = 0; u < 8; ++u) {
        vals[u] = __expf(vals[u] - m);
        s += vals[u];
    }
    #pragma unroll
    for (int off = 32; off >= 1; off >>= 1)
        s += __shfl_xor(s, off);
    if ((tid & 63) == 0) reds[tid >> 6] = s;
    __syncthreads();
    s = reds[0] + reds[1] + reds[2] + reds[3];

    const float inv = 1.f / s;
    #pragma unroll
    for (int u = 0; u < 8; ++u) {
        const float w = vals[u] * inv;
        ushort h, l; split2(w, h, l);
        whi[row * (size_t)N + tid + u * 256] = h;
        wlo[row * (size_t)N + tid + u * 256] = l;
    }
}

extern "C" void kernel_launch(void* const* d_in, const int* in_sizes, int n_in,
                              void* d_out, int out_size, void* d_ws, size_t ws_size,
                              hipStream_t stream)
{
    const float* x    = (const float*)d_in[0];  // (16, 2048, 1024)
    const float* y    = (const float*)d_in[1];  // (16, 2048, 1024)
    const int* ymask  = (const int*)d_in[2];    // (16, 2048)
    const float* W    = (const float*)d_in[3];  // (1024, 1024)
    const float* bias = (const float*)d_in[4];  // (1024,)
    float* out = (float*)d_out;

    const int XL = 2048, YL = 2048, D = 1024;
    const size_t XD = (size_t)XL * D;           // 2,097,152

    // workspace carve-up (44 MB; offsets in ushorts)
    ushort* Whi = (ushort*)d_ws;                // 1M ushorts
    ushort* Wlo = Whi + (1u << 20);
    ushort* aHi = Wlo + (1u << 20);             // 4M ([x;y] rows hi)
    ushort* aLo = aHi + (4u << 20);             // 4M
    float*  sc  = (float*)aHi;                  // 16 MB alias (a dead after proj)
    ushort* yThi = aLo + (4u << 20);            // 2M (1024 x 2048)
    ushort* yTlo = yThi + (2u << 20);
    ushort* pHi  = yTlo + (2u << 20);           // 4M ([xp;yp] hi)
    ushort* pLo  = pHi + (4u << 20);
    ushort* wHi  = pHi;                         // 4M alias (p dead after scores)
    ushort* wLo  = pLo;

    split_arr<<<dim3((D * D / 4) / 256), dim3(256), 0, stream>>>(W, Whi, Wlo, D * D / 4);

    for (int b = 0; b < 16; ++b) {
        const float* xb = x + (size_t)b * XD;
        const float* yb = y + (size_t)b * XD;
        const int*   mb = ymask + (size_t)b * YL;
        float*       ob = out + (size_t)b * XD;

        // splits: x rows -> a[0:2048], y rows -> a[2048:4096], yT -> yT splits
        split_arr<<<dim3((int)(XD / 4) / 256), dim3(256), 0, stream>>>(xb, aHi, aLo, (int)(XD / 4));
        split_transpose<<<dim3(D / 32, YL / 32), dim3(32, 8), 0, stream>>>(
            yb, aHi + XD, aLo + XD, yThi, yTlo, YL, D);

        // p = relu([x;y] @ W^T + bias), M=4096 (fills all 256 CUs)
        gemm_split<1><<<dim3(D / 128, 4096 / 128), dim3(256), 0, stream>>>(
            aHi, aLo, Whi, Wlo, bias, nullptr, nullptr, pHi, pLo, 4096, D, D);

        // sc = xp @ yp^T, masked
        gemm_split<2><<<dim3(YL / 128, XL / 128), dim3(256), 0, stream>>>(
            pHi, pLo, pHi + XD, pLo + XD, nullptr, mb, sc, nullptr, nullptr, XL, YL, D);

        softmax_split<<<dim3(XL), dim3(256), 0, stream>>>(sc, wHi, wLo, YL);

        // out_b = w @ yT^T  (i.e. sum_y w[x,y] * y[y,d])
        gemm_split<0><<<dim3(D / 128, XL / 128), dim3(256), 0, stream>>>(
            wHi, wLo, yThi, yTlo, nullptr, nullptr, ob, nullptr, nullptr, XL, D, YL);
    }
}

// Round 3
// 1297.602 us; speedup vs baseline: 4.7688x; 2.5849x over previous
//
#include <hip/hip_runtime.h>
#include <math.h>
#include <stdint.h>

// B=16, XL=YL=2048, D=1024.
// Batched pipeline (groups of G batches, G adaptive to ws_size):
//   p  = relu([x;y] @ W^T + bias)   (z-batched, 3-pass split-bf16 MFMA) -> split bf16
//   sc = xp @ yp^T (+mask)          (z-batched, 3-pass)                 -> fp32
//   w  = softmax rows(sc)                                               -> bf16
//   out= w @ yT^T                   (z-batched, 1-pass plain bf16)      -> fp32
//
// Workspace per batch: regionA (a splits / sc alias) 16MB | yT 4MB | p splits (w alias) 16MB
// Plus W splits 4MB. G = max {16,8,4,2,1} fitting ws_size.

typedef __attribute__((ext_vector_type(8))) short bf16x8;
typedef __attribute__((ext_vector_type(4))) float f32x4;

__device__ __forceinline__ ushort f32_bf16_rne(float f) {
    uint32_t u = __float_as_uint(f);
    u += 0x7fffu + ((u >> 16) & 1u);
    return (ushort)(u >> 16);
}
__device__ __forceinline__ float bf16_f32(ushort h) {
    return __uint_as_float((uint32_t)h << 16);
}
__device__ __forceinline__ void split2(float f, ushort& h, ushort& l) {
    h = f32_bf16_rne(f);
    l = f32_bf16_rne(f - bf16_f32(h));
}
__device__ __forceinline__ void ld16(ushort* lds, const ushort* g) {
    __builtin_amdgcn_global_load_lds(
        (__attribute__((address_space(1))) void*)(g),
        (__attribute__((address_space(3))) void*)(lds), 16, 0, 0);
}

// C = A @ B^T (A: MxK, B: NxK, both k-contiguous), z-batched via strides (elements).
// PASSES==3: split-bf16 AhiBhi + AhiBlo + AloBhi.  PASSES==1: plain bf16 AhiBhi.
// EPI 0: fp32 C.  EPI 1: relu(C+bias[n]) -> split bf16.  EPI 2: mask[n] ? -inf : C -> fp32.
template<int EPI, int PASSES>
__global__ __launch_bounds__(256) void gemm_split(
    const ushort* __restrict__ Ahi, const ushort* __restrict__ Alo, size_t sA,
    const ushort* __restrict__ Bhi, const ushort* __restrict__ Blo, size_t sB,
    const float* __restrict__ bias, const int* __restrict__ mask, int sMask,
    float* __restrict__ Cf, ushort* __restrict__ Chi, ushort* __restrict__ Clo, size_t sC,
    int M, int N, int K)
{
    __shared__ ushort lds[(PASSES == 3) ? 16384 : 8192];
    ushort* AsH = lds;
    ushort* BsH = lds + 4096;
    ushort* AsL = (PASSES == 3) ? (lds + 8192) : nullptr;
    ushort* BsL = (PASSES == 3) ? (lds + 12288) : nullptr;

    const int z = blockIdx.z;
    const int tid  = threadIdx.x;
    const int lane = tid & 63;
    const int wv   = tid >> 6;
    const int m0 = blockIdx.y * 128;
    const int n0 = blockIdx.x * 128;

    // staging: 128 rows x 32 k (64 B/row); chunk0 rows 0..63, chunk1 rows 64..127
    const int b0 = wv * 1024 + lane * 16;
    const int r0 = b0 >> 6;
    const int c0 = (b0 & 63) >> 1;

    const ushort* gAh = Ahi + (size_t)z * sA + (size_t)m0 * K;
    const ushort* gBh = Bhi + (size_t)z * sB + (size_t)n0 * K;
    const ushort* gAl = (PASSES == 3) ? (Alo + (size_t)z * sA + (size_t)m0 * K) : nullptr;
    const ushort* gBl = (PASSES == 3) ? (Blo + (size_t)z * sB + (size_t)n0 * K) : nullptr;
    const size_t oA0 = (size_t)r0 * K + c0;
    const size_t oA1 = (size_t)(r0 + 64) * K + c0;

    const int fr = lane & 15;
    const int fq = lane >> 4;
    const int koff = fq * 8;
    const int wm = (wv >> 1) * 64;
    const int wn = (wv & 1) * 64;

    f32x4 acc[4][4];
    #pragma unroll
    for (int i = 0; i < 4; ++i)
        #pragma unroll
        for (int j = 0; j < 4; ++j)
            acc[i][j] = (f32x4){0.f, 0.f, 0.f, 0.f};

    for (int k0 = 0; k0 < K; k0 += 32) {
        ld16(AsH + wv * 512, gAh + oA0 + k0);  ld16(AsH + 2048 + wv * 512, gAh + oA1 + k0);
        ld16(BsH + wv * 512, gBh + oA0 + k0);  ld16(BsH + 2048 + wv * 512, gBh + oA1 + k0);
        if constexpr (PASSES == 3) {
            ld16(AsL + wv * 512, gAl + oA0 + k0);  ld16(AsL + 2048 + wv * 512, gAl + oA1 + k0);
            ld16(BsL + wv * 512, gBl + oA0 + k0);  ld16(BsL + 2048 + wv * 512, gBl + oA1 + k0);
        }
        __syncthreads();

        bf16x8 a[4], b[4];
        #pragma unroll
        for (int i = 0; i < 4; ++i)
            a[i] = *(const bf16x8*)&AsH[(wm + i * 16 + fr) * 32 + koff];
        #pragma unroll
        for (int j = 0; j < 4; ++j)
            b[j] = *(const bf16x8*)&BsH[(wn + j * 16 + fr) * 32 + koff];
        #pragma unroll
        for (int i = 0; i < 4; ++i)
            #pragma unroll
            for (int j = 0; j < 4; ++j)
                acc[i][j] = __builtin_amdgcn_mfma_f32_16x16x32_bf16(a[i], b[j], acc[i][j], 0, 0, 0);
        if constexpr (PASSES == 3) {
            bf16x8 t[4];
            #pragma unroll
            for (int j = 0; j < 4; ++j)
                t[j] = *(const bf16x8*)&BsL[(wn + j * 16 + fr) * 32 + koff];
            #pragma unroll
            for (int i = 0; i < 4; ++i)
                #pragma unroll
                for (int j = 0; j < 4; ++j)
                    acc[i][j] = __builtin_amdgcn_mfma_f32_16x16x32_bf16(a[i], t[j], acc[i][j], 0, 0, 0);
            #pragma unroll
            for (int i = 0; i < 4; ++i)
                a[i] = *(const bf16x8*)&AsL[(wm + i * 16 + fr) * 32 + koff];
            #pragma unroll
            for (int i = 0; i < 4; ++i)
                #pragma unroll
                for (int j = 0; j < 4; ++j)
                    acc[i][j] = __builtin_amdgcn_mfma_f32_16x16x32_bf16(a[i], b[j], acc[i][j], 0, 0, 0);
        }
        __syncthreads();
    }

    // epilogue: within 16x16 fragment, col = fr, row = fq*4 + r
    #pragma unroll
    for (int j = 0; j < 4; ++j) {
        const int col = n0 + wn + j * 16 + fr;
        float bb = 0.f;
        int mk = 0;
        if constexpr (EPI == 1) bb = bias[col];
        if constexpr (EPI == 2) mk = mask[(size_t)z * sMask + col];
        #pragma unroll
        for (int i = 0; i < 4; ++i) {
            const int row = m0 + wm + i * 16 + fq * 4;
            #pragma unroll
            for (int r = 0; r < 4; ++r) {
                const float v = acc[i][j][r];
                const size_t idx = (size_t)z * sC + (size_t)(row + r) * N + col;
                if constexpr (EPI == 0) {
                    Cf[idx] = v;
                } else if constexpr (EPI == 1) {
                    float u = fmaxf(v + bb, 0.f);
                    ushort h, l; split2(u, h, l);
                    Chi[idx] = h; Clo[idx] = l;
                } else {
                    Cf[idx] = mk ? -INFINITY : v;
                }
            }
        }
    }
}

// fp32 -> bf16 hi/lo split, 4 elems/thread, z-batched
__global__ __launch_bounds__(256) void split_arr(const float* __restrict__ in,
    ushort* __restrict__ hi, ushort* __restrict__ lo, size_t sIn4, size_t sOut)
{
    const size_t z = blockIdx.z;
    const int i = blockIdx.x * 256 + threadIdx.x;
    const float4 v = reinterpret_cast<const float4*>(in)[z * sIn4 + i];
    ushort4 h, l;
    split2(v.x, h.x, l.x);
    split2(v.y, h.y, l.y);
    split2(v.z, h.z, l.z);
    split2(v.w, h.w, l.w);
    reinterpret_cast<ushort4*>(hi + z * sOut)[i] = h;
    reinterpret_cast<ushort4*>(lo + z * sOut)[i] = l;
}

// y (2048x1024 fp32) -> row splits (rhi,rlo) + transposed plain-bf16 (tT: 1024x2048), z-batched
__global__ __launch_bounds__(256) void split_transpose(const float* __restrict__ y,
    ushort* __restrict__ rhi, ushort* __restrict__ rlo, ushort* __restrict__ tT,
    size_t sIn, size_t sR, size_t sT)
{
    __shared__ float tile[32][33];
    const size_t z = blockIdx.z;
    const int R = 2048, C = 1024;
    const float* yb = y + z * sIn;
    const int tx = threadIdx.x & 31, ty = (threadIdx.x >> 5);
    const int c0 = blockIdx.x * 32, r0 = blockIdx.y * 32;
    #pragma unroll
    for (int k = 0; k < 4; ++k) {
        const int r = r0 + ty + k * 8;
        const float v = yb[(size_t)r * C + c0 + tx];
        tile[ty + k * 8][tx] = v;
        ushort h, l; split2(v, h, l);
        rhi[z * sR + (size_t)r * C + c0 + tx] = h;
        rlo[z * sR + (size_t)r * C + c0 + tx] = l;
    }
    __syncthreads();
    #pragma unroll
    for (int k = 0; k < 4; ++k) {
        const int c = c0 + ty + k * 8;
        tT[z * sT + (size_t)c * R + r0 + tx] = f32_bf16_rne(tile[tx][ty + k * 8]);
    }
}

// row softmax over N=2048 -> plain bf16 weights; grid.x = G*2048 rows
__global__ __launch_bounds__(256) void softmax_bf16(const float* __restrict__ S,
    ushort* __restrict__ Wout, size_t sS, size_t sW)
{
    const size_t row = blockIdx.x;
    const size_t b = row >> 11, r = row & 2047;
    const float* p = S + b * sS + r * 2048;
    ushort* q = Wout + b * sW + r * 2048;
    const int tid = threadIdx.x;

    float vals[8];
    float m = -INFINITY;
    #pragma unroll
    for (int u = 0; u < 8; ++u) {
        vals[u] = p[tid + u * 256];
        m = fmaxf(m, vals[u]);
    }
    #pragma unroll
    for (int off = 32; off >= 1; off >>= 1)
        m = fmaxf(m, __shfl_xor(m, off));

    __shared__ float redm[4], reds[4];
    if ((tid & 63) == 0) redm[tid >> 6] = m;
    __syncthreads();
    m = fmaxf(fmaxf(redm[0], redm[1]), fmaxf(redm[2], redm[3]));

    float s = 0.f;
    #pragma unroll
    for (int u = 0; u < 8; ++u) {
        vals[u] = __expf(vals[u] - m);
        s += vals[u];
    }
    #pragma unroll
    for (int off = 32; off >= 1; off >>= 1)
        s += __shfl_xor(s, off);
    if ((tid & 63) == 0) reds[tid >> 6] = s;
    __syncthreads();
    s = reds[0] + reds[1] + reds[2] + reds[3];

    const float inv = 1.f / s;
    #pragma unroll
    for (int u = 0; u < 8; ++u)
        q[tid + u * 256] = f32_bf16_rne(vals[u] * inv);
}

extern "C" void kernel_launch(void* const* d_in, const int* in_sizes, int n_in,
                              void* d_out, int out_size, void* d_ws, size_t ws_size,
                              hipStream_t stream)
{
    const float* x    = (const float*)d_in[0];  // (16, 2048, 1024)
    const float* y    = (const float*)d_in[1];  // (16, 2048, 1024)
    const int* ymask  = (const int*)d_in[2];    // (16, 2048)
    const float* W    = (const float*)d_in[3];  // (1024, 1024)
    const float* bias = (const float*)d_in[4];  // (1024,)
    float* out = (float*)d_out;

    const size_t BD = 2097152;          // 2048*1024 elems per batch matrix
    const size_t perBatch = 16777216ull + 4194304ull + 16777216ull; // 37,748,736 B

    int G = 16;
    while (G > 1 && 4194304ull + (size_t)G * perBatch > ws_size) G >>= 1;

    uint8_t* wsb = (uint8_t*)d_ws;
    ushort* Whi = (ushort*)wsb;                         // 2 MB
    ushort* Wlo = Whi + (1u << 20);                     // 2 MB
    uint8_t* regionA = wsb + (4u << 20);                // G * 16 MB (a splits / sc alias)
    uint8_t* regionT = regionA + (size_t)G * 16777216;  // G * 4 MB  (yT bf16)
    uint8_t* regionP = regionT + (size_t)G * 4194304;   // G * 16 MB (p splits / w alias)

    ushort* aHi0 = (ushort*)regionA;                    // per-batch stride 8,388,608 ush
    ushort* aLo0 = (ushort*)(regionA + 8388608);
    float*  sc0  = (float*)regionA;                     // per-batch stride 4,194,304 f32
    ushort* yT0  = (ushort*)regionT;                    // per-batch stride 2,097,152 ush
    ushort* pHi0 = (ushort*)regionP;                    // per-batch stride 8,388,608 ush
    ushort* pLo0 = (ushort*)(regionP + 8388608);
    ushort* w0   = pHi0;                                // alias (p dead after scores)

    // W split (once)
    split_arr<<<dim3(1024, 1, 1), dim3(256), 0, stream>>>(W, Whi, Wlo, 0, 0);

    for (int bs = 0; bs < 16; bs += G) {
        const float* xg = x + (size_t)bs * BD;
        const float* yg = y + (size_t)bs * BD;

        // x rows -> a[0:2048] splits
        split_arr<<<dim3(2048, 1, G), dim3(256), 0, stream>>>(
            xg, aHi0, aLo0, BD / 4, 8388608);
        // y rows -> a[2048:4096] splits; yT plain bf16
        split_transpose<<<dim3(32, 64, G), dim3(256), 0, stream>>>(
            yg, aHi0 + BD, aLo0 + BD, yT0, BD, 8388608, BD);

        // p = relu([x;y] @ W^T + bias): M=4096, N=1024, K=1024
        gemm_split<1, 3><<<dim3(8, 32, G), dim3(256), 0, stream>>>(
            aHi0, aLo0, 8388608, Whi, Wlo, 0, bias, nullptr, 0,
            nullptr, pHi0, pLo0, 8388608, 4096, 1024, 1024);

        // sc = xp @ yp^T (masked): M=N=2048, K=1024
        gemm_split<2, 3><<<dim3(16, 16, G), dim3(256), 0, stream>>>(
            pHi0, pLo0, 8388608, pHi0 + BD, pLo0 + BD, 8388608,
            nullptr, ymask + (size_t)bs * 2048, 2048,
            sc0, nullptr, nullptr, 4194304, 2048, 2048, 1024);

        // softmax rows -> bf16 w
        softmax_bf16<<<dim3(G * 2048), dim3(256), 0, stream>>>(
            sc0, w0, 4194304, 8388608);

        // out = w @ yT^T: M=2048, N=1024, K=2048 (1-pass bf16)
        gemm_split<0, 1><<<dim3(8, 16, G), dim3(256), 0, stream>>>(
            w0, nullptr, 8388608, yT0, nullptr, BD, nullptr, nullptr, 0,
            out + (size_t)bs * BD, nullptr, nullptr, BD, 2048, 1024, 2048);
    }
}

// Round 4
// 977.684 us; speedup vs baseline: 6.3292x; 1.3272x over previous
//
#include <hip/hip_runtime.h>
#include <math.h>
#include <stdint.h>

// B=16, XL=YL=2048, D=1024. fp16 2-pass pipeline, virtual-K=2048 GEMMs:
//   proj : p = relu([x;y] @ W^T + b)  A=[xyHi|xyLo], B=[W16|W16]  -> pHi,pLo (fp16 split)
//   score: sc = xp @ yp^T (+mask)     A=[pHi|pLo],  B=[ypHi|ypHi] -> fp32
//   soft : w = softmax(sc)            -> fp16
//   out  : out = w @ yT^T             A=[w|w+1024], B=[yT|yT+1024]-> fp32
// GEMM: 256x256 tile, BK=32, 8 waves (2x4), QUAD-buffered LDS (128KB),
// counted vmcnt(8) across raw s_barrier (loads for tiles t+2,t+3 stay in flight).

typedef __attribute__((ext_vector_type(8))) _Float16 f16x8;
typedef __attribute__((ext_vector_type(4))) float f32x4;

__device__ __forceinline__ ushort h2u(_Float16 h) { return __builtin_bit_cast(ushort, h); }

__device__ __forceinline__ void splitf(float f, ushort& h, ushort& l) {
    _Float16 hh = (_Float16)f;
    _Float16 ll = (_Float16)(f - (float)hh);
    h = h2u(hh); l = h2u(ll);
}

__device__ __forceinline__ void ld16(const ushort* g, ushort* l) {
    __builtin_amdgcn_global_load_lds(
        (__attribute__((address_space(1))) void*)(g),
        (__attribute__((address_space(3))) void*)(l), 16, 0, 0);
}

// C = A @ B^T, A: Mx1024ish (2 K-segments), B likewise; virtual K = 2048, nt=64 steps of 32.
// EPI 0: fp32 C. EPI 1: relu(C+bias[n]) -> fp16 split (Chi,Clo). EPI 2: mask -> -inf, fp32.
template<int EPI>
__global__ __launch_bounds__(512) void gemm256(
    const ushort* __restrict__ A0, const ushort* __restrict__ A1, int sdA, size_t zsA,
    const ushort* __restrict__ B0, const ushort* __restrict__ B1, int sdB, size_t zsB,
    const float* __restrict__ bias, const int* __restrict__ mask, int zsMask,
    float* __restrict__ Cf, ushort* __restrict__ Chi, ushort* __restrict__ Clo, size_t zsC,
    int M, int N, int ntHalf)
{
    __shared__ ushort lds[65536];   // 128KB: A bufs [0,32768) ush, B bufs [32768,65536)

    const int z = blockIdx.z;
    const int tid = threadIdx.x;
    const int lane = tid & 63;
    const int wv = tid >> 6;        // 0..7
    const int wm = wv >> 2;         // 0..1 (M half)
    const int wn = wv & 3;          // 0..3 (N quarter)
    const int m0 = blockIdx.y * 256;
    const int n0 = blockIdx.x * 256;
    const int nt = ntHalf * 2;

    A0 += (size_t)z * zsA; A1 += (size_t)z * zsA;
    B0 += (size_t)z * zsB; B1 += (size_t)z * zsB;

    // staging map: tile 256 rows x 32 k (64B/row). chunk c covers rows [c*128, c*128+128).
    // thread tid -> byte off = c*8192 + tid*16 -> row = off>>6, kelem = (off&63)>>1
    const int row0 = (tid * 16) >> 6;          // 0..127
    const int ke0  = ((tid * 16) & 63) >> 1;   // 0,8,16,24
    const size_t aoff0 = (size_t)(m0 + row0) * sdA + ke0;
    const size_t aoff1 = (size_t)(m0 + row0 + 128) * sdA + ke0;
    const size_t boff0 = (size_t)(n0 + row0) * sdB + ke0;
    const size_t boff1 = (size_t)(n0 + row0 + 128) * sdB + ke0;

    auto stage = [&](int buf, int step) {
        const int s32 = (step < ntHalf ? step : step - ntHalf) * 32;
        const ushort* Ab = (step < ntHalf ? A0 : A1) + s32;
        const ushort* Bb = (step < ntHalf ? B0 : B1) + s32;
        ushort* la = lds + buf * 8192;           // 16KB buffer
        ushort* lb = lds + 32768 + buf * 8192;
        ld16(Ab + aoff0, la + tid * 8);
        ld16(Ab + aoff1, la + 4096 + tid * 8);
        ld16(Bb + boff0, lb + tid * 8);
        ld16(Bb + boff1, lb + 4096 + tid * 8);
    };

    const int fr = lane & 15;
    const int fq = lane >> 4;
    const int abyte = (wm * 128 + fr) * 64 + fq * 16;   // + m*1024
    const int bbyte = (wn * 64 + fr) * 64 + fq * 16;    // + n*1024

    f32x4 acc[8][4];
    #pragma unroll
    for (int m = 0; m < 8; ++m)
        #pragma unroll
        for (int n = 0; n < 4; ++n)
            acc[m][n] = (f32x4){0.f, 0.f, 0.f, 0.f};

    auto compute = [&](int buf) {
        const char* la = (const char*)lds + buf * 16384;
        const char* lb = (const char*)lds + 65536 + buf * 16384;
        f16x8 a[8], b[4];
        #pragma unroll
        for (int m = 0; m < 8; ++m)
            a[m] = *(const f16x8*)(la + abyte + m * 1024);
        #pragma unroll
        for (int n = 0; n < 4; ++n)
            b[n] = *(const f16x8*)(lb + bbyte + n * 1024);
        __builtin_amdgcn_s_setprio(1);
        #pragma unroll
        for (int m = 0; m < 8; ++m)
            #pragma unroll
            for (int n = 0; n < 4; ++n)
                acc[m][n] = __builtin_amdgcn_mfma_f32_16x16x32_f16(a[m], b[n], acc[m][n], 0, 0, 0);
        __builtin_amdgcn_s_setprio(0);
    };

    // prologue: stage tiles 0,1,2; wait tile0 (12 in flight -> <=8)
    stage(0, 0); stage(1, 1); stage(2, 2);
    asm volatile("s_waitcnt vmcnt(8)" ::: "memory");
    __builtin_amdgcn_s_barrier();
    asm volatile("" ::: "memory");

    int t = 0;
    for (; t < nt - 3; ++t) {
        stage((t + 3) & 3, t + 3);          // in flight: t+1,t+2,t+3 = 12
        compute(t & 3);
        asm volatile("s_waitcnt vmcnt(8)" ::: "memory");   // drain tile t+1
        __builtin_amdgcn_s_barrier();
        asm volatile("" ::: "memory");
    }
    compute(t & 3);                          // t = nt-3
    asm volatile("s_waitcnt vmcnt(4)" ::: "memory");       // drain tile nt-2
    __builtin_amdgcn_s_barrier();
    asm volatile("" ::: "memory");
    ++t;
    compute(t & 3);                          // nt-2
    asm volatile("s_waitcnt vmcnt(0)" ::: "memory");       // drain tile nt-1
    __builtin_amdgcn_s_barrier();
    asm volatile("" ::: "memory");
    ++t;
    compute(t & 3);                          // nt-1

    // epilogue: within 16x16 frag, col = fr, row = fq*4 + r
    #pragma unroll
    for (int n = 0; n < 4; ++n) {
        const int col = n0 + wn * 64 + n * 16 + fr;
        float bb = 0.f;
        int mk = 0;
        if constexpr (EPI == 1) bb = bias[col];
        if constexpr (EPI == 2) mk = mask[(size_t)z * zsMask + col];
        #pragma unroll
        for (int m = 0; m < 8; ++m) {
            const int row = m0 + wm * 128 + m * 16 + fq * 4;
            #pragma unroll
            for (int r = 0; r < 4; ++r) {
                const float v = acc[m][n][r];
                const size_t idx = (size_t)z * zsC + (size_t)(row + r) * N + col;
                if constexpr (EPI == 0) {
                    Cf[idx] = v;
                } else if constexpr (EPI == 1) {
                    const float u = fmaxf(v + bb, 0.f);
                    ushort h, l; splitf(u, h, l);
                    Chi[idx] = h; Clo[idx] = l;
                } else {
                    Cf[idx] = mk ? -INFINITY : v;
                }
            }
        }
    }
}

// fp32 -> fp16 hi/lo split, 4 elems/thread, z-batched
__global__ __launch_bounds__(256) void split_x(const float* __restrict__ in,
    ushort* __restrict__ hi, ushort* __restrict__ lo, size_t sIn4, size_t sOut)
{
    const size_t z = blockIdx.z;
    const int i = blockIdx.x * 256 + threadIdx.x;
    const float4 v = reinterpret_cast<const float4*>(in)[z * sIn4 + i];
    ushort4 h, l;
    splitf(v.x, h.x, l.x);
    splitf(v.y, h.y, l.y);
    splitf(v.z, h.z, l.z);
    splitf(v.w, h.w, l.w);
    reinterpret_cast<ushort4*>(hi + z * sOut)[i] = h;
    reinterpret_cast<ushort4*>(lo + z * sOut)[i] = l;
}

// W fp32 -> plain fp16
__global__ __launch_bounds__(256) void cvtW(const float* __restrict__ in, ushort* __restrict__ o)
{
    const int i = blockIdx.x * 256 + threadIdx.x;
    const float4 v = reinterpret_cast<const float4*>(in)[i];
    ushort4 h;
    h.x = h2u((_Float16)v.x); h.y = h2u((_Float16)v.y);
    h.z = h2u((_Float16)v.z); h.w = h2u((_Float16)v.w);
    reinterpret_cast<ushort4*>(o)[i] = h;
}

// y (2048x1024 fp32) -> row splits fp16 (rhi,rlo) + transposed plain fp16 (1024x2048)
__global__ __launch_bounds__(256) void split_transpose(const float* __restrict__ y,
    ushort* __restrict__ rhi, ushort* __restrict__ rlo, ushort* __restrict__ tT,
    size_t sIn, size_t sR, size_t sT)
{
    __shared__ float tile[32][33];
    const size_t z = blockIdx.z;
    const int C = 1024, R = 2048;
    const float* yb = y + z * sIn;
    const int tx = threadIdx.x & 31, ty = threadIdx.x >> 5;
    const int c0 = blockIdx.x * 32, r0 = blockIdx.y * 32;
    #pragma unroll
    for (int k = 0; k < 4; ++k) {
        const int r = r0 + ty + k * 8;
        const float v = yb[(size_t)r * C + c0 + tx];
        tile[ty + k * 8][tx] = v;
        ushort h, l; splitf(v, h, l);
        rhi[z * sR + (size_t)r * C + c0 + tx] = h;
        rlo[z * sR + (size_t)r * C + c0 + tx] = l;
    }
    __syncthreads();
    #pragma unroll
    for (int k = 0; k < 4; ++k) {
        const int c = c0 + ty + k * 8;
        tT[z * sT + (size_t)c * R + r0 + tx] = h2u((_Float16)tile[tx][ty + k * 8]);
    }
}

// row softmax over 2048 -> plain fp16; grid.x = G*2048 rows
__global__ __launch_bounds__(256) void softmax_f16(const float* __restrict__ S,
    ushort* __restrict__ Wout, size_t sS, size_t sW)
{
    const size_t row = blockIdx.x;
    const size_t b = row >> 11, r = row & 2047;
    const float* p = S + b * sS + r * 2048;
    ushort* q = Wout + b * sW + r * 2048;
    const int tid = threadIdx.x;

    float vals[8];
    float m = -INFINITY;
    #pragma unroll
    for (int u = 0; u < 8; ++u) {
        vals[u] = p[tid + u * 256];
        m = fmaxf(m, vals[u]);
    }
    #pragma unroll
    for (int off = 32; off >= 1; off >>= 1)
        m = fmaxf(m, __shfl_xor(m, off));

    __shared__ float redm[4], reds[4];
    if ((tid & 63) == 0) redm[tid >> 6] = m;
    __syncthreads();
    m = fmaxf(fmaxf(redm[0], redm[1]), fmaxf(redm[2], redm[3]));

    float s = 0.f;
    #pragma unroll
    for (int u = 0; u < 8; ++u) {
        vals[u] = __expf(vals[u] - m);
        s += vals[u];
    }
    #pragma unroll
    for (int off = 32; off >= 1; off >>= 1)
        s += __shfl_xor(s, off);
    if ((tid & 63) == 0) reds[tid >> 6] = s;
    __syncthreads();
    s = reds[0] + reds[1] + reds[2] + reds[3];

    const float inv = 1.f / s;
    #pragma unroll
    for (int u = 0; u < 8; ++u)
        q[tid + u * 256] = h2u((_Float16)(vals[u] * inv));
}

extern "C" void kernel_launch(void* const* d_in, const int* in_sizes, int n_in,
                              void* d_out, int out_size, void* d_ws, size_t ws_size,
                              hipStream_t stream)
{
    const float* x    = (const float*)d_in[0];  // (16, 2048, 1024)
    const float* y    = (const float*)d_in[1];  // (16, 2048, 1024)
    const int* ymask  = (const int*)d_in[2];    // (16, 2048)
    const float* W    = (const float*)d_in[3];  // (1024, 1024)
    const float* bias = (const float*)d_in[4];  // (1024,)
    float* out = (float*)d_out;

    const size_t BD = 2097152;                  // 2048*1024

    // per batch: region1 16MB (xyHi 8 + xyLo 8; sc fp32 aliases all 16)
    //            pHi 8MB | pLo 8MB (w fp16 aliases) | yT 4MB        => 36MB
    const size_t perBatch = 37748736ull;
    int G = 16;
    while (G > 1 && 2097152ull + (size_t)G * perBatch > ws_size) G >>= 1;

    uint8_t* wsb = (uint8_t*)d_ws;
    ushort* W16 = (ushort*)wsb;                          // 2 MB
    uint8_t* r1  = wsb + 2097152;                        // G * 16MB
    uint8_t* rpH = r1 + (size_t)G * 16777216;            // G * 8MB
    uint8_t* rpL = rpH + (size_t)G * 8388608;            // G * 8MB
    uint8_t* ryT = rpL + (size_t)G * 8388608;            // G * 4MB

    ushort* xyHi = (ushort*)r1;        // z-stride 8388608 ush; xyLo = +4194304
    float*  sc   = (float*)r1;         // z-stride 4194304 f32
    ushort* pHi  = (ushort*)rpH;       // z-stride 4194304 ush
    ushort* pLo  = (ushort*)rpL;       // z-stride 4194304 ush; w aliases
    ushort* yT   = (ushort*)ryT;       // z-stride 2097152 ush

    cvtW<<<dim3(1024), dim3(256), 0, stream>>>(W, W16);

    for (int bs = 0; bs < 16; bs += G) {
        const float* xg = x + (size_t)bs * BD;
        const float* yg = y + (size_t)bs * BD;

        // x -> xy rows [0,2048) split
        split_x<<<dim3(2048, 1, G), dim3(256), 0, stream>>>(
            xg, xyHi, xyHi + 4194304, BD / 4, 8388608);
        // y -> xy rows [2048,4096) split + yT plain fp16
        split_transpose<<<dim3(32, 64, G), dim3(256), 0, stream>>>(
            yg, xyHi + BD, xyHi + 4194304 + BD, yT, BD, 8388608, BD);

        // proj: M=4096, N=1024, Kv=2048 ([xyHi|xyLo] x [W|W])
        gemm256<1><<<dim3(4, 16, G), dim3(512), 0, stream>>>(
            xyHi, xyHi + 4194304, 1024, 8388608,
            W16, W16, 1024, 0,
            bias, nullptr, 0,
            nullptr, pHi, pLo, 4194304, 4096, 1024, 32);

        // scores: M=N=2048, Kv=2048 ([xpHi|xpLo] x [ypHi|ypHi]), masked
        gemm256<2><<<dim3(8, 8, G), dim3(512), 0, stream>>>(
            pHi, pLo, 1024, 4194304,
            pHi + BD, pHi + BD, 1024, 4194304,
            nullptr, ymask + (size_t)bs * 2048, 2048,
            sc, nullptr, nullptr, 4194304, 2048, 2048, 32);

        // softmax -> w (aliases pLo)
        softmax_f16<<<dim3(G * 2048), dim3(256), 0, stream>>>(
            sc, pLo, 4194304, 4194304);

        // out: M=2048, N=1024, Kv=2048 ([w|w+1024] x [yT|yT+1024])
        gemm256<0><<<dim3(4, 8, G), dim3(512), 0, stream>>>(
            pLo, pLo + 1024, 2048, 4194304,
            yT, yT + 1024, 2048, 2097152,
            nullptr, nullptr, 0,
            out + (size_t)bs * BD, nullptr, nullptr, BD, 2048, 1024, 32);
    }
}

// Round 5
// 685.980 us; speedup vs baseline: 9.0206x; 1.4252x over previous
//
#include <hip/hip_runtime.h>
#include <math.h>
#include <stdint.h>

// B=16, XL=YL=2048, D=1024. Plain-fp16 1-pass pipeline (fp32 accum everywhere):
//   proj : p = relu([x;y]16 @ W16^T + b)   K=1024  -> pHi fp16
//   score: sc = xp @ yp^T (+mask)          K=1024  -> fp32
//   soft : w = softmax(sc)                          -> fp16 (aliases pHi)
//   out  : out = w @ yT^T                  K=2048  -> fp32
// GEMM: 256x256 tile, BK=32, 8 waves (2x4), QUAD-buffered LDS (128KB),
// counted vmcnt(8) across raw s_barrier (2-3 tiles always in flight).

typedef __attribute__((ext_vector_type(8))) _Float16 f16x8;
typedef __attribute__((ext_vector_type(4))) float f32x4;

__device__ __forceinline__ ushort h2u(_Float16 h) { return __builtin_bit_cast(ushort, h); }

__device__ __forceinline__ void ld16(const ushort* g, ushort* l) {
    __builtin_amdgcn_global_load_lds(
        (__attribute__((address_space(1))) void*)(g),
        (__attribute__((address_space(3))) void*)(l), 16, 0, 0);
}

// C = A @ B^T; A,B fp16 k-contiguous, K split into 2 virtual segments (A0/A1,B0/B1),
// nt = 2*ntHalf steps of 32. z-batched via element strides.
// EPI 0: fp32 C. EPI 1: relu(C+bias[n]) -> fp16 Chi. EPI 2: mask -> -inf, fp32.
template<int EPI>
__global__ __launch_bounds__(512) void gemm256(
    const ushort* __restrict__ A0, const ushort* __restrict__ A1, int sdA, size_t zsA,
    const ushort* __restrict__ B0, const ushort* __restrict__ B1, int sdB, size_t zsB,
    const float* __restrict__ bias, const int* __restrict__ mask, int zsMask,
    float* __restrict__ Cf, ushort* __restrict__ Chi, size_t zsC,
    int M, int N, int ntHalf)
{
    __shared__ ushort lds[65536];   // 128KB: A bufs [0,32768) ush, B bufs [32768,65536)

    const int z = blockIdx.z;
    const int tid = threadIdx.x;
    const int lane = tid & 63;
    const int wv = tid >> 6;        // 0..7
    const int wm = wv >> 2;         // 0..1 (M half)
    const int wn = wv & 3;          // 0..3 (N quarter)
    const int m0 = blockIdx.y * 256;
    const int n0 = blockIdx.x * 256;
    const int nt = ntHalf * 2;

    A0 += (size_t)z * zsA; A1 += (size_t)z * zsA;
    B0 += (size_t)z * zsB; B1 += (size_t)z * zsB;

    // staging map: tile 256 rows x 32 k (64B/row); thread tid loads 16B
    const int row0 = (tid * 16) >> 6;          // 0..127
    const int ke0  = ((tid * 16) & 63) >> 1;   // 0,8,16,24
    const size_t aoff0 = (size_t)(m0 + row0) * sdA + ke0;
    const size_t aoff1 = (size_t)(m0 + row0 + 128) * sdA + ke0;
    const size_t boff0 = (size_t)(n0 + row0) * sdB + ke0;
    const size_t boff1 = (size_t)(n0 + row0 + 128) * sdB + ke0;

    auto stage = [&](int buf, int step) {
        const int s32 = (step < ntHalf ? step : step - ntHalf) * 32;
        const ushort* Ab = (step < ntHalf ? A0 : A1) + s32;
        const ushort* Bb = (step < ntHalf ? B0 : B1) + s32;
        ushort* la = lds + buf * 8192;
        ushort* lb = lds + 32768 + buf * 8192;
        ld16(Ab + aoff0, la + tid * 8);
        ld16(Ab + aoff1, la + 4096 + tid * 8);
        ld16(Bb + boff0, lb + tid * 8);
        ld16(Bb + boff1, lb + 4096 + tid * 8);
    };

    const int fr = lane & 15;
    const int fq = lane >> 4;
    const int abyte = (wm * 128 + fr) * 64 + fq * 16;   // + m*1024
    const int bbyte = (wn * 64 + fr) * 64 + fq * 16;    // + n*1024

    f32x4 acc[8][4];
    #pragma unroll
    for (int m = 0; m < 8; ++m)
        #pragma unroll
        for (int n = 0; n < 4; ++n)
            acc[m][n] = (f32x4){0.f, 0.f, 0.f, 0.f};

    auto compute = [&](int buf) {
        const char* la = (const char*)lds + buf * 16384;
        const char* lb = (const char*)lds + 65536 + buf * 16384;
        f16x8 a[8], b[4];
        #pragma unroll
        for (int m = 0; m < 8; ++m)
            a[m] = *(const f16x8*)(la + abyte + m * 1024);
        #pragma unroll
        for (int n = 0; n < 4; ++n)
            b[n] = *(const f16x8*)(lb + bbyte + n * 1024);
        __builtin_amdgcn_s_setprio(1);
        #pragma unroll
        for (int m = 0; m < 8; ++m)
            #pragma unroll
            for (int n = 0; n < 4; ++n)
                acc[m][n] = __builtin_amdgcn_mfma_f32_16x16x32_f16(a[m], b[n], acc[m][n], 0, 0, 0);
        __builtin_amdgcn_s_setprio(0);
    };

    // prologue: stage tiles 0,1,2; wait tile0 (12 in flight -> <=8)
    stage(0, 0); stage(1, 1); stage(2, 2);
    asm volatile("s_waitcnt vmcnt(8)" ::: "memory");
    __builtin_amdgcn_s_barrier();
    asm volatile("" ::: "memory");

    int t = 0;
    for (; t < nt - 3; ++t) {
        stage((t + 3) & 3, t + 3);          // in flight: t+1,t+2,t+3 = 12
        compute(t & 3);
        asm volatile("s_waitcnt vmcnt(8)" ::: "memory");   // drain tile t+1
        __builtin_amdgcn_s_barrier();
        asm volatile("" ::: "memory");
    }
    compute(t & 3);                          // nt-3
    asm volatile("s_waitcnt vmcnt(4)" ::: "memory");
    __builtin_amdgcn_s_barrier();
    asm volatile("" ::: "memory");
    ++t;
    compute(t & 3);                          // nt-2
    asm volatile("s_waitcnt vmcnt(0)" ::: "memory");
    __builtin_amdgcn_s_barrier();
    asm volatile("" ::: "memory");
    ++t;
    compute(t & 3);                          // nt-1

    // epilogue: within 16x16 frag, col = fr, row = fq*4 + r
    #pragma unroll
    for (int n = 0; n < 4; ++n) {
        const int col = n0 + wn * 64 + n * 16 + fr;
        float bb = 0.f;
        int mk = 0;
        if constexpr (EPI == 1) bb = bias[col];
        if constexpr (EPI == 2) mk = mask[(size_t)z * zsMask + col];
        #pragma unroll
        for (int m = 0; m < 8; ++m) {
            const int row = m0 + wm * 128 + m * 16 + fq * 4;
            #pragma unroll
            for (int r = 0; r < 4; ++r) {
                const float v = acc[m][n][r];
                const size_t idx = (size_t)z * zsC + (size_t)(row + r) * N + col;
                if constexpr (EPI == 0) {
                    Cf[idx] = v;
                } else if constexpr (EPI == 1) {
                    Chi[idx] = h2u((_Float16)fmaxf(v + bb, 0.f));
                } else {
                    Cf[idx] = mk ? -INFINITY : v;
                }
            }
        }
    }
}

// fp32 -> fp16, 4 elems/thread, z-batched
__global__ __launch_bounds__(256) void cvt_f16(const float* __restrict__ in,
    ushort* __restrict__ o, size_t sIn4, size_t sOut)
{
    const size_t z = blockIdx.z;
    const int i = blockIdx.x * 256 + threadIdx.x;
    const float4 v = reinterpret_cast<const float4*>(in)[z * sIn4 + i];
    ushort4 h;
    h.x = h2u((_Float16)v.x); h.y = h2u((_Float16)v.y);
    h.z = h2u((_Float16)v.z); h.w = h2u((_Float16)v.w);
    reinterpret_cast<ushort4*>(o + z * sOut)[i] = h;
}

// y (2048x1024 fp32) -> fp16 rows (rH: 2048x1024) + fp16 transpose (tT: 1024x2048)
__global__ __launch_bounds__(256) void cvt_transpose(const float* __restrict__ y,
    ushort* __restrict__ rH, ushort* __restrict__ tT,
    size_t sIn, size_t sR, size_t sT)
{
    __shared__ float tile[32][33];
    const size_t z = blockIdx.z;
    const int C = 1024, R = 2048;
    const float* yb = y + z * sIn;
    const int tx = threadIdx.x & 31, ty = threadIdx.x >> 5;
    const int c0 = blockIdx.x * 32, r0 = blockIdx.y * 32;
    #pragma unroll
    for (int k = 0; k < 4; ++k) {
        const int r = r0 + ty + k * 8;
        const float v = yb[(size_t)r * C + c0 + tx];
        tile[ty + k * 8][tx] = v;
        rH[z * sR + (size_t)r * C + c0 + tx] = h2u((_Float16)v);
    }
    __syncthreads();
    #pragma unroll
    for (int k = 0; k < 4; ++k) {
        const int c = c0 + ty + k * 8;
        tT[z * sT + (size_t)c * R + r0 + tx] = h2u((_Float16)tile[tx][ty + k * 8]);
    }
}

// row softmax over 2048 -> fp16; grid.x = G*2048 rows; float4 loads
__global__ __launch_bounds__(256) void softmax_f16(const float* __restrict__ S,
    ushort* __restrict__ Wout, size_t sS, size_t sW)
{
    const size_t row = blockIdx.x;
    const size_t b = row >> 11, r = row & 2047;
    const float4* p4 = reinterpret_cast<const float4*>(S + b * sS + r * 2048);
    ushort4* q4 = reinterpret_cast<ushort4*>(Wout + b * sW + r * 2048);
    const int tid = threadIdx.x;

    float4 v0 = p4[tid];
    float4 v1 = p4[tid + 256];
    float m = fmaxf(fmaxf(fmaxf(v0.x, v0.y), fmaxf(v0.z, v0.w)),
                    fmaxf(fmaxf(v1.x, v1.y), fmaxf(v1.z, v1.w)));
    #pragma unroll
    for (int off = 32; off >= 1; off >>= 1)
        m = fmaxf(m, __shfl_xor(m, off));

    __shared__ float redm[4], reds[4];
    if ((tid & 63) == 0) redm[tid >> 6] = m;
    __syncthreads();
    m = fmaxf(fmaxf(redm[0], redm[1]), fmaxf(redm[2], redm[3]));

    float e[8];
    e[0] = __expf(v0.x - m); e[1] = __expf(v0.y - m);
    e[2] = __expf(v0.z - m); e[3] = __expf(v0.w - m);
    e[4] = __expf(v1.x - m); e[5] = __expf(v1.y - m);
    e[6] = __expf(v1.z - m); e[7] = __expf(v1.w - m);
    float s = ((e[0] + e[1]) + (e[2] + e[3])) + ((e[4] + e[5]) + (e[6] + e[7]));
    #pragma unroll
    for (int off = 32; off >= 1; off >>= 1)
        s += __shfl_xor(s, off);
    if ((tid & 63) == 0) reds[tid >> 6] = s;
    __syncthreads();
    s = reds[0] + reds[1] + reds[2] + reds[3];

    const float inv = 1.f / s;
    ushort4 o0, o1;
    o0.x = h2u((_Float16)(e[0] * inv)); o0.y = h2u((_Float16)(e[1] * inv));
    o0.z = h2u((_Float16)(e[2] * inv)); o0.w = h2u((_Float16)(e[3] * inv));
    o1.x = h2u((_Float16)(e[4] * inv)); o1.y = h2u((_Float16)(e[5] * inv));
    o1.z = h2u((_Float16)(e[6] * inv)); o1.w = h2u((_Float16)(e[7] * inv));
    q4[tid] = o0;
    q4[tid + 256] = o1;
}

extern "C" void kernel_launch(void* const* d_in, const int* in_sizes, int n_in,
                              void* d_out, int out_size, void* d_ws, size_t ws_size,
                              hipStream_t stream)
{
    const float* x    = (const float*)d_in[0];  // (16, 2048, 1024)
    const float* y    = (const float*)d_in[1];  // (16, 2048, 1024)
    const int* ymask  = (const int*)d_in[2];    // (16, 2048)
    const float* W    = (const float*)d_in[3];  // (1024, 1024)
    const float* bias = (const float*)d_in[4];  // (1024,)
    float* out = (float*)d_out;

    const size_t BD = 2097152;                  // 2048*1024

    // per batch: R1 16MB (xyHi fp16 8MB in [0,8); sc fp32 aliases all 16)
    //            R2 8MB pHi fp16 (w fp16 aliases after scores) | R3 4MB yT  => 28MB
    const size_t perBatch = 29360128ull;
    int G = 16;
    while (G > 1 && 2097152ull + (size_t)G * perBatch > ws_size) G >>= 1;

    uint8_t* wsb = (uint8_t*)d_ws;
    ushort* W16 = (ushort*)wsb;                          // 2 MB
    uint8_t* r1  = wsb + 2097152;                        // G * 16MB
    uint8_t* r2  = r1 + (size_t)G * 16777216;            // G * 8MB
    uint8_t* r3  = r2 + (size_t)G * 8388608;             // G * 4MB

    ushort* xyHi = (ushort*)r1;        // z-stride 8388608 ush (uses first 8MB)
    float*  sc   = (float*)r1;         // z-stride 4194304 f32 (16MB)
    ushort* pHi  = (ushort*)r2;        // z-stride 4194304 ush; w aliases
    ushort* yT   = (ushort*)r3;        // z-stride 2097152 ush

    cvt_f16<<<dim3(1024, 1, 1), dim3(256), 0, stream>>>(W, W16, 0, 0);

    for (int bs = 0; bs < 16; bs += G) {
        const float* xg = x + (size_t)bs * BD;
        const float* yg = y + (size_t)bs * BD;

        // x -> xy rows [0,2048) fp16
        cvt_f16<<<dim3(2048, 1, G), dim3(256), 0, stream>>>(
            xg, xyHi, BD / 4, 8388608);
        // y -> xy rows [2048,4096) fp16 + yT fp16
        cvt_transpose<<<dim3(32, 64, G), dim3(256), 0, stream>>>(
            yg, xyHi + BD, yT, BD, 8388608, BD);

        // proj: M=4096, N=1024, K=1024 (segments at k=512)
        gemm256<1><<<dim3(4, 16, G), dim3(512), 0, stream>>>(
            xyHi, xyHi + 512, 1024, 8388608,
            W16, W16 + 512, 1024, 0,
            bias, nullptr, 0,
            nullptr, pHi, 4194304, 4096, 1024, 16);

        // scores: M=N=2048, K=1024, masked
        gemm256<2><<<dim3(8, 8, G), dim3(512), 0, stream>>>(
            pHi, pHi + 512, 1024, 4194304,
            pHi + BD, pHi + BD + 512, 1024, 4194304,
            nullptr, ymask + (size_t)bs * 2048, 2048,
            sc, nullptr, 4194304, 2048, 2048, 16);

        // softmax -> w (aliases pHi region; pHi dead after scores)
        softmax_f16<<<dim3(G * 2048), dim3(256), 0, stream>>>(
            sc, pHi, 4194304, 4194304);

        // out: M=2048, N=1024, K=2048 ([w|w+1024] x [yT|yT+1024])
        gemm256<0><<<dim3(4, 8, G), dim3(512), 0, stream>>>(
            pHi, pHi + 1024, 2048, 4194304,
            yT, yT + 1024, 2048, 2097152,
            nullptr, nullptr, 0,
            out + (size_t)bs * BD, nullptr, BD, 2048, 1024, 32);
    }
}

// Round 6
// 654.549 us; speedup vs baseline: 9.4538x; 1.0480x over previous
//
#include <hip/hip_runtime.h>
#include <math.h>
#include <stdint.h>

// B=16, XL=YL=2048, D=1024. Plain-fp16 1-pass pipeline (fp32 accum everywhere):
//   proj : p = relu([x;y]16 @ W16^T + b)   K=1024  -> pHi fp16
//   score: sc = xp @ yp^T (+mask)          K=1024  -> fp32
//   soft : w = softmax(sc)                          -> fp16 (aliases pHi)
//   out  : out = w @ yT^T                  K=2048  -> fp32
// GEMM: 256x256 tile, BK=32, 8 waves (2x4), QUAD-buffered LDS (128KB),
// counted vmcnt(8) across raw s_barrier (2-3 tiles always in flight).
// NEW: LDS pair-row (128B) layout + XOR slot swizzle (bank-optimal ds_read_b128),
//      achieved via pre-swizzled global_load_lds SOURCE + swizzled read address
//      (linear LDS dest, rule: both-sides-or-neither). XCD-aware block swizzle.

typedef __attribute__((ext_vector_type(8))) _Float16 f16x8;
typedef __attribute__((ext_vector_type(4))) float f32x4;

__device__ __forceinline__ ushort h2u(_Float16 h) { return __builtin_bit_cast(ushort, h); }

__device__ __forceinline__ void ld16(const ushort* g, ushort* l) {
    __builtin_amdgcn_global_load_lds(
        (__attribute__((address_space(1))) void*)(g),
        (__attribute__((address_space(3))) void*)(l), 16, 0, 0);
}

// C = A @ B^T; A,B fp16 k-contiguous, K split into 2 virtual segments (A0/A1,B0/B1),
// nt = 2*ntHalf steps of 32. z-batched via element strides.
// EPI 0: fp32 C. EPI 1: relu(C+bias[n]) -> fp16 Chi. EPI 2: mask -> -inf, fp32.
template<int EPI>
__global__ __launch_bounds__(512) void gemm256(
    const ushort* __restrict__ A0, const ushort* __restrict__ A1, int sdA, size_t zsA,
    const ushort* __restrict__ B0, const ushort* __restrict__ B1, int sdB, size_t zsB,
    const float* __restrict__ bias, const int* __restrict__ mask, int zsMask,
    float* __restrict__ Cf, ushort* __restrict__ Chi, size_t zsC,
    int M, int N, int ntHalf)
{
    __shared__ ushort lds[65536];   // 128KB: A bufs [0,32768) ush, B bufs [32768,65536)

    // --- XCD-aware bijective block swizzle (all grids divisible by 8) ---
    const int gx = gridDim.x, gxy = gx * gridDim.y;
    const int total = gxy * gridDim.z;
    int h = blockIdx.z * gxy + blockIdx.y * gx + blockIdx.x;
    h = (h & 7) * (total >> 3) + (h >> 3);
    const int z = h / gxy;
    const int rem = h - z * gxy;
    const int by = rem / gx;
    const int bx = rem - by * gx;

    const int tid = threadIdx.x;
    const int lane = tid & 63;
    const int wv = tid >> 6;        // 0..7
    const int wm = wv >> 2;         // 0..1 (M half)
    const int wn = wv & 3;          // 0..3 (N quarter)
    const int m0 = by * 256;
    const int n0 = bx * 256;
    const int nt = ntHalf * 2;

    A0 += (size_t)z * zsA; A1 += (size_t)z * zsA;
    B0 += (size_t)z * zsB; B1 += (size_t)z * zsB;

    // --- staging map with swizzle ---
    // LDS layout per 16KB buffer: 128 pair-rows x 128B; pair p holds rows {2p,2p+1},
    // 8 slots of 16B; logical slot s = (row&1)*4 + kq stored at s' = s ^ (p&7).
    // Linear dest o = tid*16 (+8192 for rows+128). Source is inverse-permuted:
    const int sp   = tid & 7;               // stored slot at this dest
    const int pp   = tid >> 3;              // pair (0..63 per instruction)
    const int ss   = sp ^ (pp & 7);         // logical slot
    const int srow = pp * 2 + (ss >> 2);    // row within half-tile (0..127)
    const int ske  = (ss & 3) * 8;          // k element offset (ushorts)
    const size_t aoff0 = (size_t)(m0 + srow) * sdA + ske;
    const size_t aoff1 = (size_t)(m0 + srow + 128) * sdA + ske;
    const size_t boff0 = (size_t)(n0 + srow) * sdB + ske;
    const size_t boff1 = (size_t)(n0 + srow + 128) * sdB + ske;

    auto stage = [&](int buf, int step) {
        const int s32 = (step < ntHalf ? step : step - ntHalf) * 32;
        const ushort* Ab = (step < ntHalf ? A0 : A1) + s32;
        const ushort* Bb = (step < ntHalf ? B0 : B1) + s32;
        ushort* la = lds + buf * 8192;
        ushort* lb = lds + 32768 + buf * 8192;
        ld16(Ab + aoff0, la + tid * 8);
        ld16(Ab + aoff1, la + 4096 + tid * 8);
        ld16(Bb + boff0, lb + tid * 8);
        ld16(Bb + boff1, lb + 4096 + tid * 8);
    };

    // --- compute-side read addresses (same swizzle) ---
    const int fr = lane & 15;
    const int fq = lane >> 4;
    const int sl = (((fr & 1) << 2) | fq) ^ ((fr >> 1) & 7);   // swizzled slot
    const int abyte = (wm * 64 + (fr >> 1)) * 128 + sl * 16;   // + m*1024
    const int bbyte = (wn * 32 + (fr >> 1)) * 128 + sl * 16;   // + n*1024

    f32x4 acc[8][4];
    #pragma unroll
    for (int m = 0; m < 8; ++m)
        #pragma unroll
        for (int n = 0; n < 4; ++n)
            acc[m][n] = (f32x4){0.f, 0.f, 0.f, 0.f};

    auto compute = [&](int buf) {
        const char* la = (const char*)lds + buf * 16384;
        const char* lb = (const char*)lds + 65536 + buf * 16384;
        f16x8 a[8], b[4];
        #pragma unroll
        for (int m = 0; m < 8; ++m)
            a[m] = *(const f16x8*)(la + abyte + m * 1024);
        #pragma unroll
        for (int n = 0; n < 4; ++n)
            b[n] = *(const f16x8*)(lb + bbyte + n * 1024);
        __builtin_amdgcn_s_setprio(1);
        #pragma unroll
        for (int m = 0; m < 8; ++m)
            #pragma unroll
            for (int n = 0; n < 4; ++n)
                acc[m][n] = __builtin_amdgcn_mfma_f32_16x16x32_f16(a[m], b[n], acc[m][n], 0, 0, 0);
        __builtin_amdgcn_s_setprio(0);
    };

    // prologue: stage tiles 0,1,2; wait tile0 (12 in flight -> <=8)
    stage(0, 0); stage(1, 1); stage(2, 2);
    asm volatile("s_waitcnt vmcnt(8)" ::: "memory");
    __builtin_amdgcn_s_barrier();
    asm volatile("" ::: "memory");

    int t = 0;
    for (; t < nt - 3; ++t) {
        stage((t + 3) & 3, t + 3);          // in flight: t+1,t+2,t+3 = 12
        compute(t & 3);
        asm volatile("s_waitcnt vmcnt(8)" ::: "memory");   // drain tile t+1
        __builtin_amdgcn_s_barrier();
        asm volatile("" ::: "memory");
    }
    compute(t & 3);                          // nt-3
    asm volatile("s_waitcnt vmcnt(4)" ::: "memory");
    __builtin_amdgcn_s_barrier();
    asm volatile("" ::: "memory");
    ++t;
    compute(t & 3);                          // nt-2
    asm volatile("s_waitcnt vmcnt(0)" ::: "memory");
    __builtin_amdgcn_s_barrier();
    asm volatile("" ::: "memory");
    ++t;
    compute(t & 3);                          // nt-1

    // epilogue: within 16x16 frag, col = fr, row = fq*4 + r
    #pragma unroll
    for (int n = 0; n < 4; ++n) {
        const int col = n0 + wn * 64 + n * 16 + fr;
        float bb = 0.f;
        int mk = 0;
        if constexpr (EPI == 1) bb = bias[col];
        if constexpr (EPI == 2) mk = mask[(size_t)z * zsMask + col];
        #pragma unroll
        for (int m = 0; m < 8; ++m) {
            const int row = m0 + wm * 128 + m * 16 + fq * 4;
            #pragma unroll
            for (int r = 0; r < 4; ++r) {
                const float v = acc[m][n][r];
                const size_t idx = (size_t)z * zsC + (size_t)(row + r) * N + col;
                if constexpr (EPI == 0) {
                    Cf[idx] = v;
                } else if constexpr (EPI == 1) {
                    Chi[idx] = h2u((_Float16)fmaxf(v + bb, 0.f));
                } else {
                    Cf[idx] = mk ? -INFINITY : v;
                }
            }
        }
    }
}

// fp32 -> fp16, 4 elems/thread, z-batched
__global__ __launch_bounds__(256) void cvt_f16(const float* __restrict__ in,
    ushort* __restrict__ o, size_t sIn4, size_t sOut)
{
    const size_t z = blockIdx.z;
    const int i = blockIdx.x * 256 + threadIdx.x;
    const float4 v = reinterpret_cast<const float4*>(in)[z * sIn4 + i];
    ushort4 h;
    h.x = h2u((_Float16)v.x); h.y = h2u((_Float16)v.y);
    h.z = h2u((_Float16)v.z); h.w = h2u((_Float16)v.w);
    reinterpret_cast<ushort4*>(o + z * sOut)[i] = h;
}

// y (2048x1024 fp32) -> fp16 rows (rH: 2048x1024) + fp16 transpose (tT: 1024x2048)
__global__ __launch_bounds__(256) void cvt_transpose(const float* __restrict__ y,
    ushort* __restrict__ rH, ushort* __restrict__ tT,
    size_t sIn, size_t sR, size_t sT)
{
    __shared__ float tile[32][33];
    const size_t z = blockIdx.z;
    const int C = 1024, R = 2048;
    const float* yb = y + z * sIn;
    const int tx = threadIdx.x & 31, ty = threadIdx.x >> 5;
    const int c0 = blockIdx.x * 32, r0 = blockIdx.y * 32;
    #pragma unroll
    for (int k = 0; k < 4; ++k) {
        const int r = r0 + ty + k * 8;
        const float v = yb[(size_t)r * C + c0 + tx];
        tile[ty + k * 8][tx] = v;
        rH[z * sR + (size_t)r * C + c0 + tx] = h2u((_Float16)v);
    }
    __syncthreads();
    #pragma unroll
    for (int k = 0; k < 4; ++k) {
        const int c = c0 + ty + k * 8;
        tT[z * sT + (size_t)c * R + r0 + tx] = h2u((_Float16)tile[tx][ty + k * 8]);
    }
}

// row softmax over 2048 -> fp16; grid.x = G*2048 rows; float4 loads
__global__ __launch_bounds__(256) void softmax_f16(const float* __restrict__ S,
    ushort* __restrict__ Wout, size_t sS, size_t sW)
{
    const size_t row = blockIdx.x;
    const size_t b = row >> 11, r = row & 2047;
    const float4* p4 = reinterpret_cast<const float4*>(S + b * sS + r * 2048);
    ushort4* q4 = reinterpret_cast<ushort4*>(Wout + b * sW + r * 2048);
    const int tid = threadIdx.x;

    float4 v0 = p4[tid];
    float4 v1 = p4[tid + 256];
    float m = fmaxf(fmaxf(fmaxf(v0.x, v0.y), fmaxf(v0.z, v0.w)),
                    fmaxf(fmaxf(v1.x, v1.y), fmaxf(v1.z, v1.w)));
    #pragma unroll
    for (int off = 32; off >= 1; off >>= 1)
        m = fmaxf(m, __shfl_xor(m, off));

    __shared__ float redm[4], reds[4];
    if ((tid & 63) == 0) redm[tid >> 6] = m;
    __syncthreads();
    m = fmaxf(fmaxf(redm[0], redm[1]), fmaxf(redm[2], redm[3]));

    float e[8];
    e[0] = __expf(v0.x - m); e[1] = __expf(v0.y - m);
    e[2] = __expf(v0.z - m); e[3] = __expf(v0.w - m);
    e[4] = __expf(v1.x - m); e[5] = __expf(v1.y - m);
    e[6] = __expf(v1.z - m); e[7] = __expf(v1.w - m);
    float s = ((e[0] + e[1]) + (e[2] + e[3])) + ((e[4] + e[5]) + (e[6] + e[7]));
    #pragma unroll
    for (int off = 32; off >= 1; off >>= 1)
        s += __shfl_xor(s, off);
    if ((tid & 63) == 0) reds[tid >> 6] = s;
    __syncthreads();
    s = reds[0] + reds[1] + reds[2] + reds[3];

    const float inv = 1.f / s;
    ushort4 o0, o1;
    o0.x = h2u((_Float16)(e[0] * inv)); o0.y = h2u((_Float16)(e[1] * inv));
    o0.z = h2u((_Float16)(e[2] * inv)); o0.w = h2u((_Float16)(e[3] * inv));
    o1.x = h2u((_Float16)(e[4] * inv)); o1.y = h2u((_Float16)(e[5] * inv));
    o1.z = h2u((_Float16)(e[6] * inv)); o1.w = h2u((_Float16)(e[7] * inv));
    q4[tid] = o0;
    q4[tid + 256] = o1;
}

extern "C" void kernel_launch(void* const* d_in, const int* in_sizes, int n_in,
                              void* d_out, int out_size, void* d_ws, size_t ws_size,
                              hipStream_t stream)
{
    const float* x    = (const float*)d_in[0];  // (16, 2048, 1024)
    const float* y    = (const float*)d_in[1];  // (16, 2048, 1024)
    const int* ymask  = (const int*)d_in[2];    // (16, 2048)
    const float* W    = (const float*)d_in[3];  // (1024, 1024)
    const float* bias = (const float*)d_in[4];  // (1024,)
    float* out = (float*)d_out;

    const size_t BD = 2097152;                  // 2048*1024

    // per batch: R1 16MB (xyHi fp16 8MB in [0,8); sc fp32 aliases all 16)
    //            R2 8MB pHi fp16 (w fp16 aliases after scores) | R3 4MB yT  => 28MB
    const size_t perBatch = 29360128ull;
    int G = 16;
    while (G > 1 && 2097152ull + (size_t)G * perBatch > ws_size) G >>= 1;

    uint8_t* wsb = (uint8_t*)d_ws;
    ushort* W16 = (ushort*)wsb;                          // 2 MB
    uint8_t* r1  = wsb + 2097152;                        // G * 16MB
    uint8_t* r2  = r1 + (size_t)G * 16777216;            // G * 8MB
    uint8_t* r3  = r2 + (size_t)G * 8388608;             // G * 4MB

    ushort* xyHi = (ushort*)r1;        // z-stride 8388608 ush (uses first 8MB)
    float*  sc   = (float*)r1;         // z-stride 4194304 f32 (16MB)
    ushort* pHi  = (ushort*)r2;        // z-stride 4194304 ush; w aliases
    ushort* yT   = (ushort*)r3;        // z-stride 2097152 ush

    cvt_f16<<<dim3(1024, 1, 1), dim3(256), 0, stream>>>(W, W16, 0, 0);

    for (int bs = 0; bs < 16; bs += G) {
        const float* xg = x + (size_t)bs * BD;
        const float* yg = y + (size_t)bs * BD;

        // x -> xy rows [0,2048) fp16
        cvt_f16<<<dim3(2048, 1, G), dim3(256), 0, stream>>>(
            xg, xyHi, BD / 4, 8388608);
        // y -> xy rows [2048,4096) fp16 + yT fp16
        cvt_transpose<<<dim3(32, 64, G), dim3(256), 0, stream>>>(
            yg, xyHi + BD, yT, BD, 8388608, BD);

        // proj: M=4096, N=1024, K=1024 (segments at k=512)
        gemm256<1><<<dim3(4, 16, G), dim3(512), 0, stream>>>(
            xyHi, xyHi + 512, 1024, 8388608,
            W16, W16 + 512, 1024, 0,
            bias, nullptr, 0,
            nullptr, pHi, 4194304, 4096, 1024, 16);

        // scores: M=N=2048, K=1024, masked
        gemm256<2><<<dim3(8, 8, G), dim3(512), 0, stream>>>(
            pHi, pHi + 512, 1024, 4194304,
            pHi + BD, pHi + BD + 512, 1024, 4194304,
            nullptr, ymask + (size_t)bs * 2048, 2048,
            sc, nullptr, 4194304, 2048, 2048, 16);

        // softmax -> w (aliases pHi region; pHi dead after scores)
        softmax_f16<<<dim3(G * 2048), dim3(256), 0, stream>>>(
            sc, pHi, 4194304, 4194304);

        // out: M=2048, N=1024, K=2048 ([w|w+1024] x [yT|yT+1024])
        gemm256<0><<<dim3(4, 8, G), dim3(512), 0, stream>>>(
            pHi, pHi + 1024, 2048, 4194304,
            yT, yT + 1024, 2048, 2097152,
            nullptr, nullptr, 0,
            out + (size_t)bs * BD, nullptr, BD, 2048, 1024, 32);
    }
}